// Round 17
// baseline (23.957 us; speedup 1.0000x reference)
//
#include <hip/hip_runtime.h>
#include <math.h>

// Chamfer loss, B=8, C=3, M=N=4096, fp32 — MFMA, round 17.
//
// sq[m][n] = s2[m] + d2[n] - 2 s.d as a K=16 bf16 GEMM with hi/lo split:
//   query vec  = [-2xh,-2xh,-2xl,-2xl | y.. | z.. | s2h,s2l,1,1]
//   ref vec    = [ xh,  xl,  xh,  xl  | y.. | z.. | 1,1,d2h,d2l]
//
// Round-17 = round-16 (22.0 us best) + ONE structural change: SWAPPED MFMA
// operands — acc = mfma(bfrag, afrag). C's lane dim (col = lane&31, m74/m101)
// becomes the QUERY ROW, the 16 regs hold 16 ref cols -> min-over-cols is a
// lane-local 15-op balanced tree per MFMA (same VALU count as before) and the
// 80-shfl butterfly (ds_bpermute = LDS pipe, ~7.7K cyc/CU) collapses to ONE
// __shfl_xor(v,32). Accumulators: 2 f32x16 -> 2 scalars (-30 VGPR).
// reg->n mapping is irrelevant: min over all regs/tiles covers all cols.
// KEEP (r16): XOR swizzle c^((c>>3)&7) (write+read conflict-free), plain
// E/O v_min chains (min3 banned, r14: +8us), lb(256,4), 1024 blocks, 32KB
// LDS, 512KB partials, zero memsets.

constexpr int B = 8;
constexpr int M = 4096;   // == N

typedef __attribute__((ext_vector_type(8)))  short bf16x8;
typedef __attribute__((ext_vector_type(16))) float f32x16;

__device__ inline unsigned short bf16_of(float x) {   // round-to-nearest-even
    unsigned int u = __float_as_uint(x);
    u += 0x7FFFu + ((u >> 16) & 1u);
    return (unsigned short)(u >> 16);
}
__device__ inline float bf16_to_f(unsigned short h) {
    return __uint_as_float(((unsigned int)h) << 16);
}

// balanced min tree over 16 regs — no (min,leaf) pair, no v_min3 fusion site
__device__ inline float tree_min16(const f32x16 a) {
    const float t0 = fminf(a[0],  a[1]);
    const float t1 = fminf(a[2],  a[3]);
    const float t2 = fminf(a[4],  a[5]);
    const float t3 = fminf(a[6],  a[7]);
    const float t4 = fminf(a[8],  a[9]);
    const float t5 = fminf(a[10], a[11]);
    const float t6 = fminf(a[12], a[13]);
    const float t7 = fminf(a[14], a[15]);
    const float u0 = fminf(t0, t1);
    const float u1 = fminf(t2, t3);
    const float u2 = fminf(t4, t5);
    const float u3 = fminf(t6, t7);
    return fminf(fminf(u0, u1), fminf(u2, u3));
}

// ws: part [2 cs][16 db][M] f32 @ 0   (512 KB) ; bsums [256] f32 @ 512 KB

// grid 1024 = (dir<<9 | b<<6 | rg<<1 | cs); 256 thr = 4 waves
// wave w: rows rg*128 + w*32 .. +32 ; cols cs*2048 .. +2048 (2 chunks of 1024)
__global__ __launch_bounds__(256, 4) void chamfer_main(
    const float* __restrict__ src,
    const float* __restrict__ dst,
    float* __restrict__ part)
{
    int bid = blockIdx.x;
    const int cs  = bid & 1;  bid >>= 1;
    const int rg  = bid & 31; bid >>= 5;
    const int b   = bid & 7;  bid >>= 3;
    const int dir = bid;      // 0: rows=src scan dst ; 1: rows=dst scan src

    const float* __restrict__ qry = dir ? dst : src;   // query side (rows)
    const float* __restrict__ ref = dir ? src : dst;   // reference side (cols)

    const int tid  = threadIdx.x;
    const int wave = tid >> 6;
    const int l31  = tid & 31;
    const int hf   = (tid >> 5) & 1;    // k-group within wave

    __shared__ __align__(16) unsigned short bstage[2][1024][8];  // 32 KB

    // per-lane swizzled read rows: col i*64+l31 -> i*64 + sA ; +32 -> i*64 + sB
    const int sA = l31 ^ (l31 >> 3);
    const int sB = 32 + (l31 ^ (4 | (l31 >> 3)));

    // ---- augmented query fragment (B-operand now; lane l31 = query row) ----
    bf16x8 afrag;
    {
        const int mrow = rg * 128 + wave * 32 + l31;
        const float* qb = qry + (size_t)b * 3 * M;
        const float x = qb[0 * M + mrow];
        const float y = qb[1 * M + mrow];
        const float z = qb[2 * M + mrow];
        const float s2 = x * x + y * y + z * z;
        const float xhf = bf16_to_f(bf16_of(x));
        const float yhf = bf16_to_f(bf16_of(y));
        const float zhf = bf16_to_f(bf16_of(z));
        // -2*hi exact (pow2 scale of a bf16 value)
        const unsigned short nxh = bf16_of(-2.0f * xhf), nxl = bf16_of(-2.0f * (x - xhf));
        const unsigned short nyh = bf16_of(-2.0f * yhf), nyl = bf16_of(-2.0f * (y - yhf));
        const unsigned short nzh = bf16_of(-2.0f * zhf), nzl = bf16_of(-2.0f * (z - zhf));
        const unsigned short s2h = bf16_of(s2);
        const unsigned short s2l = bf16_of(s2 - bf16_to_f(s2h));
        const unsigned short one = 0x3F80;
        bf16x8 alo, ahi;
        alo[0]=(short)nxh; alo[1]=(short)nxh; alo[2]=(short)nxl; alo[3]=(short)nxl;
        alo[4]=(short)nyh; alo[5]=(short)nyh; alo[6]=(short)nyl; alo[7]=(short)nyl;
        ahi[0]=(short)nzh; ahi[1]=(short)nzh; ahi[2]=(short)nzl; ahi[3]=(short)nzl;
        ahi[4]=(short)s2h; ahi[5]=(short)s2l; ahi[6]=(short)one; ahi[7]=(short)one;
        afrag = hf ? ahi : alo;
    }

    float fwdE = 3.0e38f, fwdO = 3.0e38f;   // scalar running mins (E/O chains)

    const f32x16 zero = {};
    const float* rb = ref + (size_t)b * 3 * M + cs * 2048;

    for (int ch = 0; ch < 2; ++ch) {
        __syncthreads();   // previous chunk fully consumed before overwrite
        {
            // stage 1024 augmented ref cols: 4 consecutive cols per thread,
            // float4 loads per coordinate row, XOR-swizzled LDS rows
            const int c0 = tid * 4;      // within-chunk col base
            const float4 vx = *reinterpret_cast<const float4*>(&rb[0 * M + ch * 1024 + c0]);
            const float4 vy = *reinterpret_cast<const float4*>(&rb[1 * M + ch * 1024 + c0]);
            const float4 vz = *reinterpret_cast<const float4*>(&rb[2 * M + ch * 1024 + c0]);
            const float xs[4] = {vx.x, vx.y, vx.z, vx.w};
            const float ys[4] = {vy.x, vy.y, vy.z, vy.w};
            const float zs[4] = {vz.x, vz.y, vz.z, vz.w};
#pragma unroll
            for (int k = 0; k < 4; ++k) {
                const float x = xs[k], y = ys[k], z = zs[k];
                const float d2 = x * x + y * y + z * z;
                const unsigned short xh = bf16_of(x), xl = bf16_of(x - bf16_to_f(xh));
                const unsigned short yh = bf16_of(y), yl = bf16_of(y - bf16_to_f(yh));
                const unsigned short zh = bf16_of(z), zl = bf16_of(z - bf16_to_f(zh));
                const unsigned short d2h = bf16_of(d2);
                const unsigned short d2l = bf16_of(d2 - bf16_to_f(d2h));
                const unsigned short one = 0x3F80;
                bf16x8 v0, v1;
                v0[0]=(short)xh; v0[1]=(short)xl; v0[2]=(short)xh; v0[3]=(short)xl;
                v0[4]=(short)yh; v0[5]=(short)yl; v0[6]=(short)yh; v0[7]=(short)yl;
                v1[0]=(short)zh; v1[1]=(short)zl; v1[2]=(short)zh; v1[3]=(short)zl;
                v1[4]=(short)one; v1[5]=(short)one; v1[6]=(short)d2h; v1[7]=(short)d2l;
                const int c = c0 + k;
                const int swz = c ^ ((c >> 3) & 7);   // bijective, both-side min
                *reinterpret_cast<bf16x8*>(&bstage[0][swz][0]) = v0;
                *reinterpret_cast<bf16x8*>(&bstage[1][swz][0]) = v1;
            }
        }
        __syncthreads();

        // 32 tiles, 2 per step: 2 ds_read_b128 + 2 SWAPPED MFMA + 2 tree-min16
#pragma unroll 4
        for (int i = 0; i < 16; ++i) {
            const bf16x8 bf0 = *reinterpret_cast<const bf16x8*>(&bstage[hf][i * 64 + sA][0]);
            const bf16x8 bf1 = *reinterpret_cast<const bf16x8*>(&bstage[hf][i * 64 + sB][0]);
            // SWAPPED: ref vecs as A-operand, query vec as B-operand ->
            // lane dim (col=lane&31) = query row; regs = 16 ref cols
            const f32x16 acc0 = __builtin_amdgcn_mfma_f32_32x32x16_bf16(bf0, afrag, zero, 0, 0, 0);
            const f32x16 acc1 = __builtin_amdgcn_mfma_f32_32x32x16_bf16(bf1, afrag, zero, 0, 0, 0);
            fwdE = fminf(fwdE, tree_min16(acc0));
            fwdO = fminf(fwdO, tree_min16(acc1));
        }
    }

    // combine E/O + the two k-half lanes (lane l and l+32 hold same query row)
    float v = fminf(fwdE, fwdO);
    v = fminf(v, __shfl_xor(v, 32));
    if (hf == 0) {    // lanes 0..31 of each wave: 32 consecutive rows, coalesced
        part[((size_t)cs * 16 + dir * 8 + b) * M + rg * 128 + wave * 32 + l31] = v;
    }
}

// 256 blocks x 256 threads: min over the 2 col-splits, sqrt, block-sum -> bsums
__global__ __launch_bounds__(256) void chamfer_reduce(
    const float* __restrict__ part, float* __restrict__ bsums)
{
    const int idx = blockIdx.x * 256 + threadIdx.x;   // [0, 2*B*M)
    const int row = idx & (M - 1);
    const int db  = idx >> 12;                        // dir*8 + b

    const float* p = part + (size_t)db * M + row;
    const float v = fminf(p[0], p[(size_t)16 * M]);

    float s = sqrtf(fmaxf(v, 0.0f));
#pragma unroll
    for (int off = 32; off > 0; off >>= 1) s += __shfl_down(s, off);
    __shared__ float partial[4];
    if ((threadIdx.x & 63) == 0) partial[threadIdx.x >> 6] = s;
    __syncthreads();
    if (threadIdx.x == 0)
        bsums[blockIdx.x] = partial[0] + partial[1] + partial[2] + partial[3];
}

// 1 block: total, scale, plain-store out[0..2] (no memset needed anywhere)
__global__ __launch_bounds__(256) void chamfer_final(
    const float* __restrict__ bsums, float* __restrict__ out)
{
    float s = bsums[threadIdx.x];
#pragma unroll
    for (int off = 32; off > 0; off >>= 1) s += __shfl_down(s, off);
    __shared__ float partial[4];
    if ((threadIdx.x & 63) == 0) partial[threadIdx.x >> 6] = s;
    __syncthreads();
    if (threadIdx.x == 0) {
        const float tot = (partial[0] + partial[1] + partial[2] + partial[3])
                        * (1.0f / (float)(B * M));   // fwd /(B*M), bwd /(B*N), M==N
        out[0] = tot;
        out[1] = tot;
        out[2] = tot;
    }
}

extern "C" void kernel_launch(void* const* d_in, const int* in_sizes, int n_in,
                              void* d_out, int out_size, void* d_ws, size_t ws_size,
                              hipStream_t stream)
{
    const float* src = (const float*)d_in[0];   // [B,3,M]
    const float* dst = (const float*)d_in[1];   // [B,3,N]
    float* out = (float*)d_out;                 // 3 floats

    float* part  = (float*)d_ws;                          // 512 KB, fully written
    float* bsums = (float*)((char*)d_ws + (1u << 19));    // 256 floats, fully written

    chamfer_main  <<<1024, 256, 0, stream>>>(src, dst, part);
    chamfer_reduce<<<256, 256, 0, stream>>>(part, bsums);
    chamfer_final <<<1, 256, 0, stream>>>(bsums, out);
}